// Round 14
// baseline (131.353 us; speedup 1.0000x reference)
//
#include <hip/hip_runtime.h>
#include <hip/hip_bf16.h>

// ---------------------------------------------------------------------------
// LayerNormGRUCell: B=16384, I=H=512
//   G = [x@W_i2h.T | h@W_h2h.T | x@W_hatW.T | h@W_hatU.T]  (16384 x 3072)
//   then per-row: LN segments + gates + tanh + lerp -> h_t (16384 x 512 fp32)
// ws layout (bf16 elements):
//   xb   @ 0         (16384*512)
//   hb   @ 8388608   (16384*512)
//   Wcat @ 16777216  (3072*512)   rows: [W_i2h;W_h2h;W_hatW;W_hatU]
//   Gb   @ 18350080  (16384*3072)
// Round-14: GEMM rebuilt as a faithful m201-style 8-phase 256^2 kernel
// (BK=64, 2-dbuf LDS, per-phase {ds_read || gload_lds || MFMA} with counted
// vmcnt(4) once per K-step) using r7's proven staging/swizzle primitives.
// ---------------------------------------------------------------------------

using f32x4 = __attribute__((ext_vector_type(4))) float;
using s16x8 = __attribute__((ext_vector_type(8))) short;

#define XB_OFF   0ull
#define HB_OFF   8388608ull
#define WB_OFF   16777216ull
#define GB_OFF   18350080ull

// 8-fp32 chunk boundaries (total 2293760 chunks = 2240*256*4)
#define CK_X_END   1048576ull
#define CK_H_END   2097152ull
#define CK_W0_END  2162688ull
#define CK_W1_END  2228224ull
#define CK_W2_END  2260992ull
#define CK_W3_END  2293760ull
#define CK_STRIDE  573440ull

__device__ __forceinline__ void async_load16(const void* g, void* l) {
  __builtin_amdgcn_global_load_lds(
      (const __attribute__((address_space(1))) unsigned int*)g,
      (__attribute__((address_space(3))) unsigned int*)l, 16, 0, 0);
}

__device__ __forceinline__ float bfraw2f(unsigned short u) {
  union { unsigned int i; float f; } c;
  c.i = ((unsigned int)u) << 16;
  return c.f;
}

// -------------------------- fp32 -> bf16 conversion ------------------------
__global__ __launch_bounds__(256) void convert_kernel(
    const float* __restrict__ x, const float* __restrict__ h,
    const float* __restrict__ w0, const float* __restrict__ w1,
    const float* __restrict__ w2, const float* __restrict__ w3,
    __hip_bfloat16* __restrict__ ws)
{
  const size_t tid0 = (size_t)blockIdx.x * 256 + threadIdx.x;
#pragma unroll
  for (int it = 0; it < 4; ++it) {
    const size_t i = tid0 + (size_t)it * CK_STRIDE;   // chunk index
    const float* src;
    __hip_bfloat16* dst;
    size_t o;
    if (i < CK_X_END)        { src = x;  dst = ws + XB_OFF;            o = i; }
    else if (i < CK_H_END)   { src = h;  dst = ws + HB_OFF;            o = i - CK_X_END; }
    else if (i < CK_W0_END)  { src = w0; dst = ws + WB_OFF;            o = i - CK_H_END; }
    else if (i < CK_W1_END)  { src = w1; dst = ws + WB_OFF + 524288;   o = i - CK_W0_END; }
    else if (i < CK_W2_END)  { src = w2; dst = ws + WB_OFF + 1048576;  o = i - CK_W1_END; }
    else                     { src = w3; dst = ws + WB_OFF + 1310720;  o = i - CK_W2_END; }
    const float4 v0 = *(const float4*)(src + 8 * o);
    const float4 v1 = *(const float4*)(src + 8 * o + 4);
    __hip_bfloat16 t8[8] = {__float2bfloat16(v0.x), __float2bfloat16(v0.y),
                            __float2bfloat16(v0.z), __float2bfloat16(v0.w),
                            __float2bfloat16(v1.x), __float2bfloat16(v1.y),
                            __float2bfloat16(v1.z), __float2bfloat16(v1.w)};
    *(uint4*)(dst + 8 * o) = *(const uint4*)t8;
  }
}

// -------------------------------- GEMM -------------------------------------
// 256x256 tile, BK=64, 8 waves (2Mx4N, per-wave 128x64, acc[8][4]).
// m201-style 8-phase schedule: K=512 = 8 K-steps x 4 phases = 32 phases.
// Phase g (s=g>>2, p=g&3, dbuf d=s&1):
//   reads:  p0: A fm0-3 kk0-1 (8) + B fn0-1 kk0-1 (4);  p1: A fm4-7 (8);
//           p2: B fn2-3 (4);  p3: none
//   stage H(g+6) (one half-tile, 2 gload_lds/thread) if g<=25
//   s_barrier; lgkmcnt(0); sched_barrier(0) [rule 18];
//   setprio(1); 16 MFMA quadrant (p0: flo*nlo, p1: fhi*nlo, p2: flo*nhi,
//   p3: fhi*nhi); setprio(0); [p3: vmcnt(4), g==27: vmcnt(0)]; s_barrier.
//
// Half-tile sequence H(4s+{0,1,2,3}) = {A-half0, B-half0, B-half1, A-half1}
// of K-step s. LDS: A(d,h) = d*32768 + h*16384; B at +65536. Within a half:
// [kk][128 rows][64 B] sub-slots -- r7's proven geometry (0 conflicts):
// staging = 16-row/1024B wave chunks, pre-swizzled source col
// ((lane&3)*16) ^ (((lane>>3)&3)<<4); read rdk = q16 ^ (((lr>>1)&3)<<4).
//
// Pipeline audit (stage lead L=6, vmcnt(4) = 2 half-tiles in flight):
//  RAW: entry wait for step s = vmcnt(4) at end of phase 4s-1: staged
//   through H(4s+5), keeps newest 2 -> retires through H(4s+3); trailing
//   barrier publishes -> phases 4s..4s+3 may read H(4s..4s+3). Prologue
//   stages H0-H5, vmcnt(4) retires H0-H3, barrier.
//  WAR: H(k) staged at phase k-6 reuses slot of H(k-8); last LDS-read of
//   H(k-8): A-halves phase 4(s-2)+1, B-halves 4(s-2)+2 -> stage phase is
//   strictly later with >=1 intervening barrier (reads drained by their
//   phase's lgkmcnt(0) before its trailing barrier).
//  vmcnt is per-wave: 2 loads per phase uniformly -> counts exact.

__device__ __forceinline__ void stage_half(const char* gbase, char* ldshalf,
                                           int row0, int kbyte,
                                           int wave, int lane) {
  const int row  = wave * 16 + (lane >> 2);                       // 0..127
  const int colb = ((lane & 3) * 16) ^ (((lane >> 3) & 3) << 4);  // pre-swz
#pragma unroll
  for (int i = 0; i < 2; ++i) {  // i = kk sub-slot
    async_load16(gbase + (size_t)(row0 + row) * 1024 + kbyte + i * 64 + colb,
                 ldshalf + i * 8192 + wave * 1024 + lane * 16);
  }
}

__global__ __launch_bounds__(512, 2) void gemm_kernel(
    const __hip_bfloat16* __restrict__ xb,
    const __hip_bfloat16* __restrict__ hb,
    const __hip_bfloat16* __restrict__ Wb,
    __hip_bfloat16* __restrict__ G)
{
  // T1: bijective XCD swizzle; nwg=768, 768%8==0, chunk=96 wgs/XCD.
  const int bid = blockIdx.x;
  const int wg  = (bid & 7) * 96 + (bid >> 3);
  const int ntl = wg % 12, mtl = wg / 12;
  const int m0 = mtl * 256, n0 = ntl * 256;
  const int seg = n0 >> 9;  // 512-wide segments: 0,1,4 -> x ; 2,3,5 -> h
  const __hip_bfloat16* A = (seg < 2 || seg == 4) ? xb : hb;

  __shared__ __align__(16) char lds[131072];  // A 64K (2dbufx2half) + B 64K

  const int tid  = threadIdx.x;
  const int lane = tid & 63;
  const int wave = tid >> 6;
  const int wm = wave >> 2, wn = wave & 3;   // 2 x 4 wave grid, 128x64 each

  const char* Ab = (const char*)A  + (size_t)m0 * 1024;  // row = 512*2 B
  const char* Bb = (const char*)Wb + (size_t)n0 * 1024;

  const int q16 = (lane >> 4) * 16;
  const int lr  = lane & 15;
  const int rdk = q16 ^ (((lr >> 1) & 3) << 4);    // r7-proven read swizzle

  // stage dispatcher for half-tile H(j): j>>2 = K-step, j&3 = which half
  auto stageH = [&](int j) {
    const int s = j >> 2, d = s & 1, t = j & 3;
    const int kb = s * 128;
    if (t == 0)      stage_half(Ab, lds + d * 32768,                 0,   kb, wave, lane);
    else if (t == 1) stage_half(Bb, lds + 65536 + d * 32768,         0,   kb, wave, lane);
    else if (t == 2) stage_half(Bb, lds + 65536 + d * 32768 + 16384, 128, kb, wave, lane);
    else             stage_half(Ab, lds + d * 32768 + 16384,         128, kb, wave, lane);
  };
  auto rdA = [&](int d, int fm, int kk) {  // fm 0..7 within the wave's half
    return *(const s16x8*)(lds + d * 32768 + wm * 16384 + kk * 8192 +
                           (fm * 16 + lr) * 64 + rdk);
  };
  auto rdB = [&](int d, int fn, int kk) {  // fn 0..3 within the wave's cols
    return *(const s16x8*)(lds + 65536 + d * 32768 + (wn >> 1) * 16384 +
                           kk * 8192 + ((wn & 1) * 64 + fn * 16 + lr) * 64 + rdk);
  };

  f32x4 acc[8][4];
#pragma unroll
  for (int i = 0; i < 8; ++i)
#pragma unroll
    for (int j = 0; j < 4; ++j) acc[i][j] = (f32x4){0.f, 0.f, 0.f, 0.f};

  // prologue: stage H0..H5 (12 loads); retire H0-H3; publish.
#pragma unroll
  for (int j = 0; j < 6; ++j) stageH(j);
  asm volatile("s_waitcnt vmcnt(4)" ::: "memory");
  __builtin_amdgcn_s_barrier();

  s16x8 aLo[4][2], aHi[4][2], bLo[2][2], bHi[2][2];

#pragma unroll
  for (int g = 0; g < 32; ++g) {
    const int s = g >> 2, p = g & 3, d = s & 1;

    // --- per-phase ds_reads (issue before barrier; drained by lgkm(0)) ---
    if (p == 0) {
#pragma unroll
      for (int fm = 0; fm < 4; ++fm)
#pragma unroll
        for (int kk = 0; kk < 2; ++kk) aLo[fm][kk] = rdA(d, fm, kk);
#pragma unroll
      for (int fn = 0; fn < 2; ++fn)
#pragma unroll
        for (int kk = 0; kk < 2; ++kk) bLo[fn][kk] = rdB(d, fn, kk);
    } else if (p == 1) {
#pragma unroll
      for (int fm = 0; fm < 4; ++fm)
#pragma unroll
        for (int kk = 0; kk < 2; ++kk) aHi[fm][kk] = rdA(d, 4 + fm, kk);
    } else if (p == 2) {
#pragma unroll
      for (int fn = 0; fn < 2; ++fn)
#pragma unroll
        for (int kk = 0; kk < 2; ++kk) bHi[fn][kk] = rdB(d, 2 + fn, kk);
    }

    // --- stage one half-tile, lead 6 ---
    if (g <= 25) stageH(g + 6);

    __builtin_amdgcn_s_barrier();
    asm volatile("s_waitcnt lgkmcnt(0)" ::: "memory");
    __builtin_amdgcn_sched_barrier(0);   // rule 18: pin MFMA below the wait

    __builtin_amdgcn_s_setprio(1);
    if (p == 0) {
#pragma unroll
      for (int fm = 0; fm < 4; ++fm)
#pragma unroll
        for (int fn = 0; fn < 2; ++fn)
#pragma unroll
          for (int kk = 0; kk < 2; ++kk)
            acc[fm][fn] = __builtin_amdgcn_mfma_f32_16x16x32_bf16(
                aLo[fm][kk], bLo[fn][kk], acc[fm][fn], 0, 0, 0);
    } else if (p == 1) {
#pragma unroll
      for (int fm = 0; fm < 4; ++fm)
#pragma unroll
        for (int fn = 0; fn < 2; ++fn)
#pragma unroll
          for (int kk = 0; kk < 2; ++kk)
            acc[4 + fm][fn] = __builtin_amdgcn_mfma_f32_16x16x32_bf16(
                aHi[fm][kk], bLo[fn][kk], acc[4 + fm][fn], 0, 0, 0);
    } else if (p == 2) {
#pragma unroll
      for (int fm = 0; fm < 4; ++fm)
#pragma unroll
        for (int fn = 0; fn < 2; ++fn)
#pragma unroll
          for (int kk = 0; kk < 2; ++kk)
            acc[fm][2 + fn] = __builtin_amdgcn_mfma_f32_16x16x32_bf16(
                aLo[fm][kk], bHi[fn][kk], acc[fm][2 + fn], 0, 0, 0);
    } else {
#pragma unroll
      for (int fm = 0; fm < 4; ++fm)
#pragma unroll
        for (int fn = 0; fn < 2; ++fn)
#pragma unroll
          for (int kk = 0; kk < 2; ++kk)
            acc[4 + fm][2 + fn] = __builtin_amdgcn_mfma_f32_16x16x32_bf16(
                aHi[fm][kk], bHi[fn][kk], acc[4 + fm][2 + fn], 0, 0, 0);
    }
    __builtin_amdgcn_s_setprio(0);

    // --- counted vmcnt once per K-step (end of p3), never 0 until g=27 ---
    if (p == 3) {
      if (g < 27)       asm volatile("s_waitcnt vmcnt(4)" ::: "memory");
      else if (g == 27) asm volatile("s_waitcnt vmcnt(0)" ::: "memory");
    }
    __builtin_amdgcn_s_barrier();
  }

  // epilogue: D lane map (verified r3): col = lane&15, row = (lane>>4)*4+reg
  const int mbase = m0 + wm * 128 + ((lane >> 4) << 2);
  const int nbase = n0 + wn * 64 + (lane & 15);
#pragma unroll
  for (int fm = 0; fm < 8; ++fm)
#pragma unroll
    for (int fn = 0; fn < 4; ++fn)
#pragma unroll
      for (int r = 0; r < 4; ++r)
        G[(size_t)(mbase + fm * 16 + r) * 3072 + nbase + fn * 16] =
            __float2bfloat16(acc[fm][fn][r]);
}

// ------------------------------ LN + gates ---------------------------------
__device__ __forceinline__ float4 block_red4(float4 v, float* red, int tid) {
#pragma unroll
  for (int off = 32; off; off >>= 1) {
    v.x += __shfl_down(v.x, off);
    v.y += __shfl_down(v.y, off);
    v.z += __shfl_down(v.z, off);
    v.w += __shfl_down(v.w, off);
  }
  __syncthreads();  // protect `red` against previous use
  if ((tid & 63) == 0) {
    const int w = tid >> 6;
    red[w * 4 + 0] = v.x; red[w * 4 + 1] = v.y;
    red[w * 4 + 2] = v.z; red[w * 4 + 3] = v.w;
  }
  __syncthreads();
  return make_float4(red[0] + red[4] + red[8]  + red[12],
                     red[1] + red[5] + red[9]  + red[13],
                     red[2] + red[6] + red[10] + red[14],
                     red[3] + red[7] + red[11] + red[15]);
}

__global__ __launch_bounds__(256) void ln_gate_kernel(
    const __hip_bfloat16* __restrict__ G,
    const __hip_bfloat16* __restrict__ hb,   // bf16 h from ws
    const float* __restrict__ b0, const float* __restrict__ b1,
    const float* __restrict__ b2, const float* __restrict__ b3,
    float* __restrict__ out)
{
  const int row = blockIdx.x;
  const int t   = threadIdx.x;
  const unsigned short* g = (const unsigned short*)(G + (size_t)row * 3072);

  __shared__ float zr[1024];
  __shared__ float red[16];

  float v0[4], v1[4];
  {
    const ushort4 u = *(const ushort4*)(g + 4 * t);
    const float4 b = *(const float4*)(b0 + 4 * t);
    v0[0] = bfraw2f(u.x) + b.x; v0[1] = bfraw2f(u.y) + b.y;
    v0[2] = bfraw2f(u.z) + b.z; v0[3] = bfraw2f(u.w) + b.w;
  }
  {
    const ushort4 u = *(const ushort4*)(g + 1024 + 4 * t);
    const float4 b = *(const float4*)(b1 + 4 * t);
    v1[0] = bfraw2f(u.x) + b.x; v1[1] = bfraw2f(u.y) + b.y;
    v1[2] = bfraw2f(u.z) + b.z; v1[3] = bfraw2f(u.w) + b.w;
  }
  float4 a;
  a.x = v0[0] + v0[1] + v0[2] + v0[3];
  a.y = v0[0]*v0[0] + v0[1]*v0[1] + v0[2]*v0[2] + v0[3]*v0[3];
  a.z = v1[0] + v1[1] + v1[2] + v1[3];
  a.w = v1[0]*v1[0] + v1[1]*v1[1] + v1[2]*v1[2] + v1[3]*v1[3];
  const float4 r01 = block_red4(a, red, t);
  const float mu0 = r01.x * (1.f / 1024.f);
  const float mu1 = r01.z * (1.f / 1024.f);
  const float rs0 = rsqrtf(r01.y * (1.f / 1024.f) - mu0 * mu0 + 1e-5f);
  const float rs1 = rsqrtf(r01.w * (1.f / 1024.f) - mu1 * mu1 + 1e-5f);

#pragma unroll
  for (int k = 0; k < 4; ++k) {
    const float pre = (v0[k] - mu0) * rs0 + (v1[k] - mu1) * rs1;
    zr[4 * t + k] = 1.f / (1.f + __expf(-pre));
  }

  float v2[2], v3[2];
  {
    const ushort2 u = *(const ushort2*)(g + 2048 + 2 * t);
    const float2 b = *(const float2*)(b2 + 2 * t);
    v2[0] = bfraw2f(u.x) + b.x; v2[1] = bfraw2f(u.y) + b.y;
  }
  {
    const ushort2 u = *(const ushort2*)(g + 2560 + 2 * t);
    const float2 b = *(const float2*)(b3 + 2 * t);
    v3[0] = bfraw2f(u.x) + b.x; v3[1] = bfraw2f(u.y) + b.y;
  }
  a.x = v2[0] + v2[1];
  a.y = v2[0]*v2[0] + v2[1]*v2[1];
  a.z = v3[0] + v3[1];
  a.w = v3[0]*v3[0] + v3[1]*v3[1];
  const float4 r23 = block_red4(a, red, t);  // syncs also publish zr[]
  const float mu2 = r23.x * (1.f / 512.f);
  const float mu3 = r23.z * (1.f / 512.f);
  const float rs2 = rsqrtf(r23.y * (1.f / 512.f) - mu2 * mu2 + 1e-5f);
  const float rs3 = rsqrtf(r23.w * (1.f / 512.f) - mu3 * mu3 + 1e-5f);

  const ushort2 hu = *(const ushort2*)((const unsigned short*)hb +
                                       (size_t)row * 512 + 2 * t);
  float o[2];
#pragma unroll
  for (int k = 0; k < 2; ++k) {
    const int j = 2 * t + k;
    const float ha = (v2[k] - mu2) * rs2;
    const float hbv = (v3[k] - mu3) * rs3;
    const float hhat = tanhf(ha + zr[512 + j] * hbv);
    const float z = zr[j];
    const float hvk = bfraw2f(k == 0 ? hu.x : hu.y);
    o[k] = (1.f - z) * hvk + z * hhat;
  }
  *(float2*)(out + (size_t)row * 512 + 2 * t) = make_float2(o[0], o[1]);
}

// ------------------------------- launcher ----------------------------------
extern "C" void kernel_launch(void* const* d_in, const int* in_sizes, int n_in,
                              void* d_out, int out_size, void* d_ws, size_t ws_size,
                              hipStream_t stream) {
  (void)in_sizes; (void)n_in; (void)out_size; (void)ws_size;
  const float* x      = (const float*)d_in[0];
  const float* h      = (const float*)d_in[1];
  const float* W_i2h  = (const float*)d_in[2];
  const float* b_i2h  = (const float*)d_in[3];
  const float* W_h2h  = (const float*)d_in[4];
  const float* b_h2h  = (const float*)d_in[5];
  const float* W_hatW = (const float*)d_in[6];
  const float* b_hatW = (const float*)d_in[7];
  const float* W_hatU = (const float*)d_in[8];
  const float* b_hatU = (const float*)d_in[9];
  float* out = (float*)d_out;
  __hip_bfloat16* ws = (__hip_bfloat16*)d_ws;

  convert_kernel<<<2240, 256, 0, stream>>>(x, h, W_i2h, W_h2h, W_hatW, W_hatU, ws);
  gemm_kernel<<<768, 512, 0, stream>>>(ws + XB_OFF, ws + HB_OFF,
                                       ws + WB_OFF, ws + GB_OFF);
  ln_gate_kernel<<<16384, 256, 0, stream>>>(ws + GB_OFF, ws + HB_OFF,
                                            b_i2h, b_h2h, b_hatW, b_hatU, out);
}

// Round 16
// 122.869 us; speedup vs baseline: 1.0690x; 1.0690x over previous
//
#include <hip/hip_runtime.h>
#include <hip/hip_bf16.h>

// ---------------------------------------------------------------------------
// LayerNormGRUCell: B=16384, I=H=512
//   G = [x@W_i2h.T | h@W_h2h.T | x@W_hatW.T | h@W_hatU.T]  (16384 x 3072)
//   then per-row: LN segments + gates + tanh + lerp -> h_t (16384 x 512 fp32)
// ws layout (bf16 elements):
//   Wcat @ 0        (3072*512)    rows: [W_i2h;W_h2h;W_hatW;W_hatU]
//   Gb   @ 1572864  (16384*3072)
// Round-16: r15 A-resident fused GEMM with the swizzle bug fixed: the A
// prologue now loads from the LINEAR source offset and writes to the
// SWIZZLED LDS position (r8's proven writeA pattern; rule 21). r15 had
// source==dest==swizzled, which cancels to identity and breaks the reads.
// ---------------------------------------------------------------------------

using f32x4 = __attribute__((ext_vector_type(4))) float;
using s16x8 = __attribute__((ext_vector_type(8))) short;

#define WB_OFF   0ull
#define GB_OFF   1572864ull

__device__ __forceinline__ void async_load16(const void* g, void* l) {
  __builtin_amdgcn_global_load_lds(
      (const __attribute__((address_space(1))) unsigned int*)g,
      (__attribute__((address_space(3))) unsigned int*)l, 16, 0, 0);
}

__device__ __forceinline__ float bfraw2f(unsigned short u) {
  union { unsigned int i; float f; } c;
  c.i = ((unsigned int)u) << 16;
  return c.f;
}

// -------------------------- fp32 -> bf16 weights only ----------------------
// vec4 boundaries: w0 131072, w1 +131072, w2 +65536, w3 +65536 = 393216 total
__global__ __launch_bounds__(256) void convert_w_kernel(
    const float* __restrict__ w0, const float* __restrict__ w1,
    const float* __restrict__ w2, const float* __restrict__ w3,
    __hip_bfloat16* __restrict__ dst)
{
  const size_t i = (size_t)blockIdx.x * 256 + threadIdx.x;  // vec4 index
  const float* src;
  __hip_bfloat16* d;
  size_t o;
  if (i < 131072ull)      { src = w0; d = dst;            o = i; }
  else if (i < 262144ull) { src = w1; d = dst + 524288;   o = i - 131072ull; }
  else if (i < 327680ull) { src = w2; d = dst + 1048576;  o = i - 262144ull; }
  else                    { src = w3; d = dst + 1310720;  o = i - 327680ull; }
  const float4 v = *(const float4*)(src + 4 * o);
  __hip_bfloat16 t4[4] = {__float2bfloat16(v.x), __float2bfloat16(v.y),
                          __float2bfloat16(v.z), __float2bfloat16(v.w)};
  *(uint2*)(d + 4 * o) = *(const uint2*)t4;
}

// -------------------------------- GEMM -------------------------------------
// 256 blocks x 512 threads, 1 block/CU. Block bid: type = bid&1 (0=X uses x,
// 1=H uses h), mband = bid>>1 (128 rows each). X n-tiles {0,1,2,3,8,9}
// (segs 0,1,4); H {4,5,6,7,10,11} (segs 2,3,5) -> one A input per block.
// Even XCDs get X blocks, odd get H (bid%8 XCD round-robin) -> per-XCD W
// working set 1.5MB < 4MB L2.
//
// LDS (163840 B = full 160 KiB):
//   A resident [kt=16][row=128][64 B] @ 0        (131072 B, bf16)
//   B ring-2   [slot=2][row=256][64 B] @ 131072  (32768 B, bf16)
// A prologue: fp32 global (LINEAR offset) -> regs -> cvt -> ds_write at the
// SWIZZLED position (rule 21: write-perm == read-perm).
// B staged via global_load_lds, pre-swizzled source (r7 primitive).
// Row swizzle swz(row)=((row>>1)&3)<<4 on 16B chunks (proven, 0 conflicts).
//
// Schedule per n-tile: 16 ktiles; entry {vmcnt(0); barrier}; read b[4],a[4];
// stage B(next ktile) into other slot; setprio(1) 16 MFMA setprio(0).
// Ring-2 WAR: slot (kt+1)&1's prior content last read at kt-1, drained
// before kt's entry barrier. Epilogue stores drain at next entry vmcnt(0).

#define B_BASE 131072

__device__ __forceinline__ void stage_B(const char* base, char* slot,
                                        int koff, int wave, int lane) {
#pragma unroll
  for (int i = 0; i < 2; ++i) {
    const int c = wave * 2 + i;
    const int row  = c * 16 + (lane >> 2);
    const int colb = ((lane & 3) * 16) ^ (((lane >> 3) & 3) << 4);  // pre-swz
    async_load16(base + (size_t)row * 1024 + koff + colb,
                 slot + c * 1024 + lane * 16);
  }
}

__global__ __launch_bounds__(512, 2) void gemm_kernel(
    const float* __restrict__ xf,
    const float* __restrict__ hf,
    const __hip_bfloat16* __restrict__ Wb,
    __hip_bfloat16* __restrict__ G)
{
  const int bid   = blockIdx.x;     // 256
  const int type  = bid & 1;        // 0 = X, 1 = H
  const int mband = bid >> 1;       // 0..127
  const int m0    = mband * 128;
  const float* Af = (type ? hf : xf) + (size_t)m0 * 512;

  __shared__ __align__(16) char lds[163840];

  const int tid  = threadIdx.x;
  const int lane = tid & 63;
  const int wave = tid >> 6;
  const int wm = wave >> 2, wn = wave & 3;   // 2 x 4 wave grid, 64x64 each

  const int lk  = (lane >> 4) * 16;
  const int lr  = lane & 15;
  const int rdk = lk ^ (((lr >> 1) & 3) << 4);     // read swizzle (A and B)

  auto rdA = [&](int kt, int fm) {
    return *(const s16x8*)(lds + kt * 8192 +
                           (wm * 64 + fm * 16 + lr) * 64 + rdk);
  };
  auto rdB = [&](int slot, int fn) {
    return *(const s16x8*)(lds + B_BASE + slot * 16384 +
                           (wn * 64 + fn * 16 + lr) * 64 + rdk);
  };

  // first B panel (n-tile list element 0)
  const int ntl0 = type ? 4 : 0;
  const char* Bb0 = (const char*)Wb + (size_t)ntl0 * 256 * 1024;

  // issue B(ktile 0) first so it's oldest in the vmem queue
  stage_B(Bb0, lds + B_BASE, 0, wave, lane);

  // ---- A prologue: fp32 -> bf16 resident LDS (once per block) ----
  // FIX (r15 bug): load from LINEAR source offset lin, write at the
  // SWIZZLED position lin ^ swz(row) -- r8's proven writeA pattern.
  {
    const int row = tid >> 2;                          // 0..127
    const int lin = (tid & 3) * 16;                    // linear byte pos
    const int cb  = lin ^ (((row >> 1) & 3) << 4);     // swizzled LDS pos
    const float* arow = Af + (size_t)row * 512 + (lin >> 1);  // linear elems
#pragma unroll
    for (int kt = 0; kt < 16; ++kt) {
      const float* p = arow + kt * 32;
      const float4 v0 = *(const float4*)p;
      const float4 v1 = *(const float4*)(p + 4);
      union { s16x8 v; __hip_bfloat16 b[8]; } u;
      u.b[0] = __float2bfloat16(v0.x); u.b[1] = __float2bfloat16(v0.y);
      u.b[2] = __float2bfloat16(v0.z); u.b[3] = __float2bfloat16(v0.w);
      u.b[4] = __float2bfloat16(v1.x); u.b[5] = __float2bfloat16(v1.y);
      u.b[6] = __float2bfloat16(v1.z); u.b[7] = __float2bfloat16(v1.w);
      *(s16x8*)(lds + kt * 8192 + row * 64 + cb) = u.v;
    }
  }
  asm volatile("s_waitcnt vmcnt(0) lgkmcnt(0)" ::: "memory");
  __builtin_amdgcn_s_barrier();

  // ---- 6 n-tiles x 16 ktiles ----
  for (int i = 0; i < 6; ++i) {
    const int ntl = (i < 4) ? (type ? i + 4 : i) : (type ? i + 6 : i + 4);
    const int ntlN = (i + 1 < 4) ? (type ? i + 5 : i + 1)
                                 : (type ? i + 7 : i + 5);   // valid for i<5
    const char* Bb  = (const char*)Wb + (size_t)ntl * 256 * 1024;
    const char* BbN = (const char*)Wb + (size_t)(i < 5 ? ntlN : ntl) * 256 * 1024;

    f32x4 acc[4][4];
#pragma unroll
    for (int a = 0; a < 4; ++a)
#pragma unroll
      for (int b = 0; b < 4; ++b) acc[a][b] = (f32x4){0.f, 0.f, 0.f, 0.f};

#pragma unroll
    for (int kt = 0; kt < 16; ++kt) {
      asm volatile("s_waitcnt vmcnt(0)" ::: "memory");  // B(this kt) resident
      __builtin_amdgcn_s_barrier();                     // + prev reads done

      const int slot = kt & 1;
      s16x8 b[4], a[4];
#pragma unroll
      for (int fn = 0; fn < 4; ++fn) b[fn] = rdB(slot, fn);
#pragma unroll
      for (int fm = 0; fm < 4; ++fm) a[fm] = rdA(kt, fm);

      if (kt < 15)
        stage_B(Bb, lds + B_BASE + ((kt + 1) & 1) * 16384, (kt + 1) * 64,
                wave, lane);
      else if (i < 5)
        stage_B(BbN, lds + B_BASE, 0, wave, lane);   // slot (16(i+1))&1 == 0

      __builtin_amdgcn_s_setprio(1);
#pragma unroll
      for (int fm = 0; fm < 4; ++fm)
#pragma unroll
        for (int fn = 0; fn < 4; ++fn)
          acc[fm][fn] = __builtin_amdgcn_mfma_f32_16x16x32_bf16(
              a[fm], b[fn], acc[fm][fn], 0, 0, 0);
      __builtin_amdgcn_s_setprio(0);
    }

    // n-tile epilogue: D lane map (verified): col=lane&15, row=(lane>>4)*4+r
    const int n0 = ntl * 256;
    const int mbase = m0 + wm * 64 + ((lane >> 4) << 2);
    const int nbase = n0 + wn * 64 + lr;
#pragma unroll
    for (int fm = 0; fm < 4; ++fm)
#pragma unroll
      for (int fn = 0; fn < 4; ++fn)
#pragma unroll
        for (int r = 0; r < 4; ++r)
          G[(size_t)(mbase + fm * 16 + r) * 3072 + nbase + fn * 16] =
              __float2bfloat16(acc[fm][fn][r]);
  }
}

// ------------------------------ LN + gates ---------------------------------
__device__ __forceinline__ float4 block_red4(float4 v, float* red, int tid) {
#pragma unroll
  for (int off = 32; off; off >>= 1) {
    v.x += __shfl_down(v.x, off);
    v.y += __shfl_down(v.y, off);
    v.z += __shfl_down(v.z, off);
    v.w += __shfl_down(v.w, off);
  }
  __syncthreads();  // protect `red` against previous use
  if ((tid & 63) == 0) {
    const int w = tid >> 6;
    red[w * 4 + 0] = v.x; red[w * 4 + 1] = v.y;
    red[w * 4 + 2] = v.z; red[w * 4 + 3] = v.w;
  }
  __syncthreads();
  return make_float4(red[0] + red[4] + red[8]  + red[12],
                     red[1] + red[5] + red[9]  + red[13],
                     red[2] + red[6] + red[10] + red[14],
                     red[3] + red[7] + red[11] + red[15]);
}

__global__ __launch_bounds__(256) void ln_gate_kernel(
    const __hip_bfloat16* __restrict__ G, const float* __restrict__ h,
    const float* __restrict__ b0, const float* __restrict__ b1,
    const float* __restrict__ b2, const float* __restrict__ b3,
    float* __restrict__ out)
{
  const int row = blockIdx.x;
  const int t   = threadIdx.x;
  const unsigned short* g = (const unsigned short*)(G + (size_t)row * 3072);

  __shared__ float zr[1024];
  __shared__ float red[16];

  float v0[4], v1[4];
  {
    const ushort4 u = *(const ushort4*)(g + 4 * t);
    const float4 b = *(const float4*)(b0 + 4 * t);
    v0[0] = bfraw2f(u.x) + b.x; v0[1] = bfraw2f(u.y) + b.y;
    v0[2] = bfraw2f(u.z) + b.z; v0[3] = bfraw2f(u.w) + b.w;
  }
  {
    const ushort4 u = *(const ushort4*)(g + 1024 + 4 * t);
    const float4 b = *(const float4*)(b1 + 4 * t);
    v1[0] = bfraw2f(u.x) + b.x; v1[1] = bfraw2f(u.y) + b.y;
    v1[2] = bfraw2f(u.z) + b.z; v1[3] = bfraw2f(u.w) + b.w;
  }
  float4 a;
  a.x = v0[0] + v0[1] + v0[2] + v0[3];
  a.y = v0[0]*v0[0] + v0[1]*v0[1] + v0[2]*v0[2] + v0[3]*v0[3];
  a.z = v1[0] + v1[1] + v1[2] + v1[3];
  a.w = v1[0]*v1[0] + v1[1]*v1[1] + v1[2]*v1[2] + v1[3]*v1[3];
  const float4 r01 = block_red4(a, red, t);
  const float mu0 = r01.x * (1.f / 1024.f);
  const float mu1 = r01.z * (1.f / 1024.f);
  const float rs0 = rsqrtf(r01.y * (1.f / 1024.f) - mu0 * mu0 + 1e-5f);
  const float rs1 = rsqrtf(r01.w * (1.f / 1024.f) - mu1 * mu1 + 1e-5f);

#pragma unroll
  for (int k = 0; k < 4; ++k) {
    const float pre = (v0[k] - mu0) * rs0 + (v1[k] - mu1) * rs1;
    zr[4 * t + k] = 1.f / (1.f + __expf(-pre));
  }

  float v2[2], v3[2];
  {
    const ushort2 u = *(const ushort2*)(g + 2048 + 2 * t);
    const float2 b = *(const float2*)(b2 + 2 * t);
    v2[0] = bfraw2f(u.x) + b.x; v2[1] = bfraw2f(u.y) + b.y;
  }
  {
    const ushort2 u = *(const ushort2*)(g + 2560 + 2 * t);
    const float2 b = *(const float2*)(b3 + 2 * t);
    v3[0] = bfraw2f(u.x) + b.x; v3[1] = bfraw2f(u.y) + b.y;
  }
  a.x = v2[0] + v2[1];
  a.y = v2[0]*v2[0] + v2[1]*v2[1];
  a.z = v3[0] + v3[1];
  a.w = v3[0]*v3[0] + v3[1]*v3[1];
  const float4 r23 = block_red4(a, red, t);  // syncs also publish zr[]
  const float mu2 = r23.x * (1.f / 512.f);
  const float mu3 = r23.z * (1.f / 512.f);
  const float rs2 = rsqrtf(r23.y * (1.f / 512.f) - mu2 * mu2 + 1e-5f);
  const float rs3 = rsqrtf(r23.w * (1.f / 512.f) - mu3 * mu3 + 1e-5f);

  const float2 hv = *(const float2*)(h + (size_t)row * 512 + 2 * t);
  float o[2];
#pragma unroll
  for (int k = 0; k < 2; ++k) {
    const int j = 2 * t + k;
    const float ha = (v2[k] - mu2) * rs2;
    const float hbv = (v3[k] - mu3) * rs3;
    const float hhat = tanhf(ha + zr[512 + j] * hbv);
    const float z = zr[j];
    const float hvk = (k == 0) ? hv.x : hv.y;
    o[k] = (1.f - z) * hvk + z * hhat;
  }
  *(float2*)(out + (size_t)row * 512 + 2 * t) = make_float2(o[0], o[1]);
}

// ------------------------------- launcher ----------------------------------
extern "C" void kernel_launch(void* const* d_in, const int* in_sizes, int n_in,
                              void* d_out, int out_size, void* d_ws, size_t ws_size,
                              hipStream_t stream) {
  (void)in_sizes; (void)n_in; (void)out_size; (void)ws_size;
  const float* x      = (const float*)d_in[0];
  const float* h      = (const float*)d_in[1];
  const float* W_i2h  = (const float*)d_in[2];
  const float* b_i2h  = (const float*)d_in[3];
  const float* W_h2h  = (const float*)d_in[4];
  const float* b_h2h  = (const float*)d_in[5];
  const float* W_hatW = (const float*)d_in[6];
  const float* b_hatW = (const float*)d_in[7];
  const float* W_hatU = (const float*)d_in[8];
  const float* b_hatU = (const float*)d_in[9];
  float* out = (float*)d_out;
  __hip_bfloat16* ws = (__hip_bfloat16*)d_ws;

  convert_w_kernel<<<1536, 256, 0, stream>>>(W_i2h, W_h2h, W_hatW, W_hatU,
                                             ws + WB_OFF);
  gemm_kernel<<<256, 512, 0, stream>>>(x, h, ws + WB_OFF, ws + GB_OFF);
  ln_gate_kernel<<<16384, 256, 0, stream>>>(ws + GB_OFF, h, b_i2h, b_h2h,
                                            b_hatW, b_hatU, out);
}

// Round 17
// 122.533 us; speedup vs baseline: 1.0720x; 1.0027x over previous
//
#include <hip/hip_runtime.h>
#include <hip/hip_bf16.h>

// ---------------------------------------------------------------------------
// LayerNormGRUCell: B=16384, I=H=512
//   G = [x@W_i2h.T | h@W_h2h.T | x@W_hatW.T | h@W_hatU.T]  (16384 x 3072)
//   then per-row: LN segments + gates + tanh + lerp -> h_t (16384 x 512 fp32)
// ws layout (bf16 elements):
//   Wcat @ 0        (3072*512)    rows: [W_i2h;W_h2h;W_hatW;W_hatU]
//   Gb   @ 1572864  (16384*3072)
// Round-17: r16 A-resident fused GEMM + A-PROLOGUE STREAMED through panel
// 0's ktile loop (r10 early-load pattern): cvt+write A(kt+1) from regs
// loaded at kt-1, hidden under panel-0 MFMAs instead of ~11us serial.
// ---------------------------------------------------------------------------

using f32x4 = __attribute__((ext_vector_type(4))) float;
using s16x8 = __attribute__((ext_vector_type(8))) short;

#define WB_OFF   0ull
#define GB_OFF   1572864ull

__device__ __forceinline__ void async_load16(const void* g, void* l) {
  __builtin_amdgcn_global_load_lds(
      (const __attribute__((address_space(1))) unsigned int*)g,
      (__attribute__((address_space(3))) unsigned int*)l, 16, 0, 0);
}

__device__ __forceinline__ float bfraw2f(unsigned short u) {
  union { unsigned int i; float f; } c;
  c.i = ((unsigned int)u) << 16;
  return c.f;
}

// -------------------------- fp32 -> bf16 weights only ----------------------
// vec4 boundaries: w0 131072, w1 +131072, w2 +65536, w3 +65536 = 393216 total
__global__ __launch_bounds__(256) void convert_w_kernel(
    const float* __restrict__ w0, const float* __restrict__ w1,
    const float* __restrict__ w2, const float* __restrict__ w3,
    __hip_bfloat16* __restrict__ dst)
{
  const size_t i = (size_t)blockIdx.x * 256 + threadIdx.x;  // vec4 index
  const float* src;
  __hip_bfloat16* d;
  size_t o;
  if (i < 131072ull)      { src = w0; d = dst;            o = i; }
  else if (i < 262144ull) { src = w1; d = dst + 524288;   o = i - 131072ull; }
  else if (i < 327680ull) { src = w2; d = dst + 1048576;  o = i - 262144ull; }
  else                    { src = w3; d = dst + 1310720;  o = i - 327680ull; }
  const float4 v = *(const float4*)(src + 4 * o);
  __hip_bfloat16 t4[4] = {__float2bfloat16(v.x), __float2bfloat16(v.y),
                          __float2bfloat16(v.z), __float2bfloat16(v.w)};
  *(uint2*)(d + 4 * o) = *(const uint2*)t4;
}

// -------------------------------- GEMM -------------------------------------
// 256 blocks x 512 threads, 1 block/CU. Block bid: type = bid&1 (0=X uses x,
// 1=H uses h), mband = bid>>1 (128 rows each). X n-tiles {0,1,2,3,8,9}
// (segs 0,1,4); H {4,5,6,7,10,11} (segs 2,3,5) -> one A input per block.
//
// LDS (163840 B = full 160 KiB):
//   A resident [kt=16][row=128][64 B] @ 0        (131072 B, bf16)
//   B ring-2   [slot=2][row=256][64 B] @ 131072  (32768 B, bf16)
// A conversion streamed through panel 0 (this round):
//   ktile kt: entry {vmcnt(0) lgkm(0); barrier} -> cvt+ds_write A(kt+1)
//   (regs loaded at kt-1; visible to readers via kt+1's entry lgkm+barrier)
//   -> ds_reads of kt -> stage B(kt+1) -> load A(kt+2) -> MFMA.
//   Index audit: writeA(kt+1) for kt<=14 (A1..A15; A0 written pre-loop);
//   loadA(kt+2) for kt<=13 (A2..A15; A0,A1 loaded pre-loop). Reads of A(kt)
//   see writes from kt-1 (lgkm drained pre-barrier). A regions write-once ->
//   no WAR. Entry vmcnt(0) retires B(kt) + A(kt+1) loads (cover >= 1 ktile).
// A write: LINEAR global source, SWIZZLED LDS pos (rule 21, r8 pattern).
// B staged via global_load_lds, pre-swizzled source (r7 primitive).
// Row swizzle swz(row)=((row>>1)&3)<<4 on 16B chunks (proven, 0 conflicts).
// Panels 1-5: r16 loop verbatim (A resident, B ring-2, vmcnt(0) entries).

#define B_BASE 131072

__device__ __forceinline__ void stage_B(const char* base, char* slot,
                                        int koff, int wave, int lane) {
#pragma unroll
  for (int i = 0; i < 2; ++i) {
    const int c = wave * 2 + i;
    const int row  = c * 16 + (lane >> 2);
    const int colb = ((lane & 3) * 16) ^ (((lane >> 3) & 3) << 4);  // pre-swz
    async_load16(base + (size_t)row * 1024 + koff + colb,
                 slot + c * 1024 + lane * 16);
  }
}

__device__ __forceinline__ void cvt_write8(void* dst, const float4& f0,
                                           const float4& f1) {
  union { s16x8 v; __hip_bfloat16 b[8]; } u;
  u.b[0] = __float2bfloat16(f0.x); u.b[1] = __float2bfloat16(f0.y);
  u.b[2] = __float2bfloat16(f0.z); u.b[3] = __float2bfloat16(f0.w);
  u.b[4] = __float2bfloat16(f1.x); u.b[5] = __float2bfloat16(f1.y);
  u.b[6] = __float2bfloat16(f1.z); u.b[7] = __float2bfloat16(f1.w);
  *(s16x8*)dst = u.v;
}

__global__ __launch_bounds__(512, 2) void gemm_kernel(
    const float* __restrict__ xf,
    const float* __restrict__ hf,
    const __hip_bfloat16* __restrict__ Wb,
    __hip_bfloat16* __restrict__ G)
{
  const int bid   = blockIdx.x;     // 256
  const int type  = bid & 1;        // 0 = X, 1 = H
  const int mband = bid >> 1;       // 0..127
  const int m0    = mband * 128;
  const float* Af = (type ? hf : xf) + (size_t)m0 * 512;

  __shared__ __align__(16) char lds[163840];

  const int tid  = threadIdx.x;
  const int lane = tid & 63;
  const int wave = tid >> 6;
  const int wm = wave >> 2, wn = wave & 3;   // 2 x 4 wave grid, 64x64 each

  const int lk  = (lane >> 4) * 16;
  const int lr  = lane & 15;
  const int rdk = lk ^ (((lr >> 1) & 3) << 4);     // read swizzle (A and B)

  auto rdA = [&](int kt, int fm) {
    return *(const s16x8*)(lds + kt * 8192 +
                           (wm * 64 + fm * 16 + lr) * 64 + rdk);
  };
  auto rdB = [&](int slot, int fn) {
    return *(const s16x8*)(lds + B_BASE + slot * 16384 +
                           (wn * 64 + fn * 16 + lr) * 64 + rdk);
  };

  // first B panel (n-tile list element 0)
  const int ntl0 = type ? 4 : 0;
  const char* Bb0 = (const char*)Wb + (size_t)ntl0 * 256 * 1024;

  // issue B(ktile 0) first so it's oldest in the vmem queue
  stage_B(Bb0, lds + B_BASE, 0, wave, lane);

  // ---- A streaming setup: LINEAR source, SWIZZLED LDS dest (rule 21) ----
  const int arow = tid >> 2;                         // 0..127
  const int alin = (tid & 3) * 16;                   // linear byte pos
  const int acb  = alin ^ (((arow >> 1) & 3) << 4);  // swizzled LDS pos
  const float* abase = Af + (size_t)arow * 512 + (alin >> 1);
  char* const awr = lds + arow * 64 + acb;           // + kt*8192

  float4 hA, hB;
  {
    const float4 a0 = *(const float4*)(abase);       // A(0)
    const float4 a1 = *(const float4*)(abase + 4);
    hA = *(const float4*)(abase + 32);               // A(1)
    hB = *(const float4*)(abase + 36);
    cvt_write8(awr, a0, a1);                         // write A(0)
  }

  // ---- panel 0: compute ntl0 while streaming A into residence ----
  {
    const int ntl1 = type ? 5 : 1;
    const char* BbN = (const char*)Wb + (size_t)ntl1 * 256 * 1024;

    f32x4 acc[4][4];
#pragma unroll
    for (int a = 0; a < 4; ++a)
#pragma unroll
      for (int b = 0; b < 4; ++b) acc[a][b] = (f32x4){0.f, 0.f, 0.f, 0.f};

#pragma unroll
    for (int kt = 0; kt < 16; ++kt) {
      asm volatile("s_waitcnt vmcnt(0) lgkmcnt(0)" ::: "memory");
      __builtin_amdgcn_s_barrier();   // B(kt) + A(kt+1) loads retired;
                                      // A(kt) writes visible

      if (kt <= 14) cvt_write8(awr + (kt + 1) * 8192, hA, hB);  // A(kt+1)

      const int slot = kt & 1;
      s16x8 b[4], a[4];
#pragma unroll
      for (int fn = 0; fn < 4; ++fn) b[fn] = rdB(slot, fn);
#pragma unroll
      for (int fm = 0; fm < 4; ++fm) a[fm] = rdA(kt, fm);

      if (kt < 15)
        stage_B(Bb0, lds + B_BASE + ((kt + 1) & 1) * 16384, (kt + 1) * 64,
                wave, lane);
      else
        stage_B(BbN, lds + B_BASE, 0, wave, lane);   // panel 1, slot 0

      if (kt <= 13) {                                 // load A(kt+2)
        hA = *(const float4*)(abase + (kt + 2) * 32);
        hB = *(const float4*)(abase + (kt + 2) * 32 + 4);
      }

      __builtin_amdgcn_s_setprio(1);
#pragma unroll
      for (int fm = 0; fm < 4; ++fm)
#pragma unroll
        for (int fn = 0; fn < 4; ++fn)
          acc[fm][fn] = __builtin_amdgcn_mfma_f32_16x16x32_bf16(
              a[fm], b[fn], acc[fm][fn], 0, 0, 0);
      __builtin_amdgcn_s_setprio(0);
    }

    // panel-0 epilogue
    const int n0 = ntl0 * 256;
    const int mbase = m0 + wm * 64 + ((lane >> 4) << 2);
    const int nbase = n0 + wn * 64 + lr;
#pragma unroll
    for (int fm = 0; fm < 4; ++fm)
#pragma unroll
      for (int fn = 0; fn < 4; ++fn)
#pragma unroll
        for (int r = 0; r < 4; ++r)
          G[(size_t)(mbase + fm * 16 + r) * 3072 + nbase + fn * 16] =
              __float2bfloat16(acc[fm][fn][r]);
  }

  // ---- panels 1..5 (A resident) -- r16 loop verbatim ----
  for (int i = 1; i < 6; ++i) {
    const int ntl = (i < 4) ? (type ? i + 4 : i) : (type ? i + 6 : i + 4);
    const int ntlN = (i + 1 < 4) ? (type ? i + 5 : i + 1)
                                 : (type ? i + 7 : i + 5);   // valid for i<5
    const char* Bb  = (const char*)Wb + (size_t)ntl * 256 * 1024;
    const char* BbN = (const char*)Wb + (size_t)(i < 5 ? ntlN : ntl) * 256 * 1024;

    f32x4 acc[4][4];
#pragma unroll
    for (int a = 0; a < 4; ++a)
#pragma unroll
      for (int b = 0; b < 4; ++b) acc[a][b] = (f32x4){0.f, 0.f, 0.f, 0.f};

#pragma unroll
    for (int kt = 0; kt < 16; ++kt) {
      asm volatile("s_waitcnt vmcnt(0)" ::: "memory");  // B(this kt) resident
      __builtin_amdgcn_s_barrier();                     // + prev reads done

      const int slot = kt & 1;
      s16x8 b[4], a[4];
#pragma unroll
      for (int fn = 0; fn < 4; ++fn) b[fn] = rdB(slot, fn);
#pragma unroll
      for (int fm = 0; fm < 4; ++fm) a[fm] = rdA(kt, fm);

      if (kt < 15)
        stage_B(Bb, lds + B_BASE + ((kt + 1) & 1) * 16384, (kt + 1) * 64,
                wave, lane);
      else if (i < 5)
        stage_B(BbN, lds + B_BASE, 0, wave, lane);   // slot (16(i+1))&1 == 0

      __builtin_amdgcn_s_setprio(1);
#pragma unroll
      for (int fm = 0; fm < 4; ++fm)
#pragma unroll
        for (int fn = 0; fn < 4; ++fn)
          acc[fm][fn] = __builtin_amdgcn_mfma_f32_16x16x32_bf16(
              a[fm], b[fn], acc[fm][fn], 0, 0, 0);
      __builtin_amdgcn_s_setprio(0);
    }

    // n-tile epilogue: D lane map (verified): col=lane&15, row=(lane>>4)*4+r
    const int n0 = ntl * 256;
    const int mbase = m0 + wm * 64 + ((lane >> 4) << 2);
    const int nbase = n0 + wn * 64 + lr;
#pragma unroll
    for (int fm = 0; fm < 4; ++fm)
#pragma unroll
      for (int fn = 0; fn < 4; ++fn)
#pragma unroll
        for (int r = 0; r < 4; ++r)
          G[(size_t)(mbase + fm * 16 + r) * 3072 + nbase + fn * 16] =
              __float2bfloat16(acc[fm][fn][r]);
  }
}

// ------------------------------ LN + gates ---------------------------------
__device__ __forceinline__ float4 block_red4(float4 v, float* red, int tid) {
#pragma unroll
  for (int off = 32; off; off >>= 1) {
    v.x += __shfl_down(v.x, off);
    v.y += __shfl_down(v.y, off);
    v.z += __shfl_down(v.z, off);
    v.w += __shfl_down(v.w, off);
  }
  __syncthreads();  // protect `red` against previous use
  if ((tid & 63) == 0) {
    const int w = tid >> 6;
    red[w * 4 + 0] = v.x; red[w * 4 + 1] = v.y;
    red[w * 4 + 2] = v.z; red[w * 4 + 3] = v.w;
  }
  __syncthreads();
  return make_float4(red[0] + red[4] + red[8]  + red[12],
                     red[1] + red[5] + red[9]  + red[13],
                     red[2] + red[6] + red[10] + red[14],
                     red[3] + red[7] + red[11] + red[15]);
}

__global__ __launch_bounds__(256) void ln_gate_kernel(
    const __hip_bfloat16* __restrict__ G, const float* __restrict__ h,
    const float* __restrict__ b0, const float* __restrict__ b1,
    const float* __restrict__ b2, const float* __restrict__ b3,
    float* __restrict__ out)
{
  const int row = blockIdx.x;
  const int t   = threadIdx.x;
  const unsigned short* g = (const unsigned short*)(G + (size_t)row * 3072);

  __shared__ float zr[1024];
  __shared__ float red[16];

  float v0[4], v1[4];
  {
    const ushort4 u = *(const ushort4*)(g + 4 * t);
    const float4 b = *(const float4*)(b0 + 4 * t);
    v0[0] = bfraw2f(u.x) + b.x; v0[1] = bfraw2f(u.y) + b.y;
    v0[2] = bfraw2f(u.z) + b.z; v0[3] = bfraw2f(u.w) + b.w;
  }
  {
    const ushort4 u = *(const ushort4*)(g + 1024 + 4 * t);
    const float4 b = *(const float4*)(b1 + 4 * t);
    v1[0] = bfraw2f(u.x) + b.x; v1[1] = bfraw2f(u.y) + b.y;
    v1[2] = bfraw2f(u.z) + b.z; v1[3] = bfraw2f(u.w) + b.w;
  }
  float4 a;
  a.x = v0[0] + v0[1] + v0[2] + v0[3];
  a.y = v0[0]*v0[0] + v0[1]*v0[1] + v0[2]*v0[2] + v0[3]*v0[3];
  a.z = v1[0] + v1[1] + v1[2] + v1[3];
  a.w = v1[0]*v1[0] + v1[1]*v1[1] + v1[2]*v1[2] + v1[3]*v1[3];
  const float4 r01 = block_red4(a, red, t);
  const float mu0 = r01.x * (1.f / 1024.f);
  const float mu1 = r01.z * (1.f / 1024.f);
  const float rs0 = rsqrtf(r01.y * (1.f / 1024.f) - mu0 * mu0 + 1e-5f);
  const float rs1 = rsqrtf(r01.w * (1.f / 1024.f) - mu1 * mu1 + 1e-5f);

#pragma unroll
  for (int k = 0; k < 4; ++k) {
    const float pre = (v0[k] - mu0) * rs0 + (v1[k] - mu1) * rs1;
    zr[4 * t + k] = 1.f / (1.f + __expf(-pre));
  }

  float v2[2], v3[2];
  {
    const ushort2 u = *(const ushort2*)(g + 2048 + 2 * t);
    const float2 b = *(const float2*)(b2 + 2 * t);
    v2[0] = bfraw2f(u.x) + b.x; v2[1] = bfraw2f(u.y) + b.y;
  }
  {
    const ushort2 u = *(const ushort2*)(g + 2560 + 2 * t);
    const float2 b = *(const float2*)(b3 + 2 * t);
    v3[0] = bfraw2f(u.x) + b.x; v3[1] = bfraw2f(u.y) + b.y;
  }
  a.x = v2[0] + v2[1];
  a.y = v2[0]*v2[0] + v2[1]*v2[1];
  a.z = v3[0] + v3[1];
  a.w = v3[0]*v3[0] + v3[1]*v3[1];
  const float4 r23 = block_red4(a, red, t);  // syncs also publish zr[]
  const float mu2 = r23.x * (1.f / 512.f);
  const float mu3 = r23.z * (1.f / 512.f);
  const float rs2 = rsqrtf(r23.y * (1.f / 512.f) - mu2 * mu2 + 1e-5f);
  const float rs3 = rsqrtf(r23.w * (1.f / 512.f) - mu3 * mu3 + 1e-5f);

  const float2 hv = *(const float2*)(h + (size_t)row * 512 + 2 * t);
  float o[2];
#pragma unroll
  for (int k = 0; k < 2; ++k) {
    const int j = 2 * t + k;
    const float ha = (v2[k] - mu2) * rs2;
    const float hbv = (v3[k] - mu3) * rs3;
    const float hhat = tanhf(ha + zr[512 + j] * hbv);
    const float z = zr[j];
    const float hvk = (k == 0) ? hv.x : hv.y;
    o[k] = (1.f - z) * hvk + z * hhat;
  }
  *(float2*)(out + (size_t)row * 512 + 2 * t) = make_float2(o[0], o[1]);
}

// ------------------------------- launcher ----------------------------------
extern "C" void kernel_launch(void* const* d_in, const int* in_sizes, int n_in,
                              void* d_out, int out_size, void* d_ws, size_t ws_size,
                              hipStream_t stream) {
  (void)in_sizes; (void)n_in; (void)out_size; (void)ws_size;
  const float* x      = (const float*)d_in[0];
  const float* h      = (const float*)d_in[1];
  const float* W_i2h  = (const float*)d_in[2];
  const float* b_i2h  = (const float*)d_in[3];
  const float* W_h2h  = (const float*)d_in[4];
  const float* b_h2h  = (const float*)d_in[5];
  const float* W_hatW = (const float*)d_in[6];
  const float* b_hatW = (const float*)d_in[7];
  const float* W_hatU = (const float*)d_in[8];
  const float* b_hatU = (const float*)d_in[9];
  float* out = (float*)d_out;
  __hip_bfloat16* ws = (__hip_bfloat16*)d_ws;

  convert_w_kernel<<<1536, 256, 0, stream>>>(W_i2h, W_h2h, W_hatW, W_hatU,
                                             ws + WB_OFF);
  gemm_kernel<<<256, 512, 0, stream>>>(x, h, ws + WB_OFF, ws + GB_OFF);
  ln_gate_kernel<<<16384, 256, 0, stream>>>(ws + GB_OFF, h, b_i2h, b_h2h,
                                            b_hatW, b_hatU, out);
}

// Round 18
// 120.644 us; speedup vs baseline: 1.0888x; 1.0157x over previous
//
#include <hip/hip_runtime.h>
#include <hip/hip_bf16.h>

// ---------------------------------------------------------------------------
// LayerNormGRUCell: B=16384, I=H=512
//   G = [x@W_i2h.T | h@W_h2h.T | x@W_hatW.T | h@W_hatU.T]  (16384 x 3072)
//   then per-row: LN segments + gates + tanh + lerp -> h_t (16384 x 512 fp32)
// ws layout (bf16 elements):
//   Wcat @ 0        (3072*512)    rows: [W_i2h;W_h2h;W_hatW;W_hatU]
//   Gb   @ 1572864  (16384*3072)
// Round-18: r17 + panels 1-5 A-FRAGMENT PREFETCH (A is resident+immutable
// after panel 0 -> issue rdA(kt+1) inside kt's MFMA cluster, hiding half the
// per-ktile LDS burst) and stage_B hoisted to just after the entry barrier
// (more cover before the next vmcnt(0) drain). Panel 0 unchanged (A-prefetch
// there would race with the streamed A writes).
// ---------------------------------------------------------------------------

using f32x4 = __attribute__((ext_vector_type(4))) float;
using s16x8 = __attribute__((ext_vector_type(8))) short;

#define WB_OFF   0ull
#define GB_OFF   1572864ull

__device__ __forceinline__ void async_load16(const void* g, void* l) {
  __builtin_amdgcn_global_load_lds(
      (const __attribute__((address_space(1))) unsigned int*)g,
      (__attribute__((address_space(3))) unsigned int*)l, 16, 0, 0);
}

__device__ __forceinline__ float bfraw2f(unsigned short u) {
  union { unsigned int i; float f; } c;
  c.i = ((unsigned int)u) << 16;
  return c.f;
}

// -------------------------- fp32 -> bf16 weights only ----------------------
// vec4 boundaries: w0 131072, w1 +131072, w2 +65536, w3 +65536 = 393216 total
__global__ __launch_bounds__(256) void convert_w_kernel(
    const float* __restrict__ w0, const float* __restrict__ w1,
    const float* __restrict__ w2, const float* __restrict__ w3,
    __hip_bfloat16* __restrict__ dst)
{
  const size_t i = (size_t)blockIdx.x * 256 + threadIdx.x;  // vec4 index
  const float* src;
  __hip_bfloat16* d;
  size_t o;
  if (i < 131072ull)      { src = w0; d = dst;            o = i; }
  else if (i < 262144ull) { src = w1; d = dst + 524288;   o = i - 131072ull; }
  else if (i < 327680ull) { src = w2; d = dst + 1048576;  o = i - 262144ull; }
  else                    { src = w3; d = dst + 1310720;  o = i - 327680ull; }
  const float4 v = *(const float4*)(src + 4 * o);
  __hip_bfloat16 t4[4] = {__float2bfloat16(v.x), __float2bfloat16(v.y),
                          __float2bfloat16(v.z), __float2bfloat16(v.w)};
  *(uint2*)(d + 4 * o) = *(const uint2*)t4;
}

// -------------------------------- GEMM -------------------------------------
// 256 blocks x 512 threads, 1 block/CU. Block bid: type = bid&1 (0=X uses x,
// 1=H uses h), mband = bid>>1 (128 rows each). X n-tiles {0,1,2,3,8,9}
// (segs 0,1,4); H {4,5,6,7,10,11} (segs 2,3,5) -> one A input per block.
//
// LDS (163840 B = full 160 KiB):
//   A resident [kt=16][row=128][64 B] @ 0        (131072 B, bf16)
//   B ring-2   [slot=2][row=256][64 B] @ 131072  (32768 B, bf16)
// Panel 0 streams the A conversion (cvt+write A(kt+1) from regs loaded at
// kt-1, hidden under panel-0 MFMAs). Panels 1-5: A-fragment prefetch
// (rdA(kt+1) inside kt's MFMA cluster; A immutable -> no race) + early
// stage_B. A write: LINEAR global source, SWIZZLED LDS pos (rule 21).
// B staged via global_load_lds, pre-swizzled source. Row swizzle
// swz(row)=((row>>1)&3)<<4 on 16B chunks (proven, 0 conflicts).
//
// Ring-2 WAR: slot (kt+1)&1's prior content last read at kt-1, whose
// ds_reads drained (lgkm before MFMA use) before kt's entry barrier ->
// staging it right after kt's entry barrier is safe.

#define B_BASE 131072

__device__ __forceinline__ void stage_B(const char* base, char* slot,
                                        int koff, int wave, int lane) {
#pragma unroll
  for (int i = 0; i < 2; ++i) {
    const int c = wave * 2 + i;
    const int row  = c * 16 + (lane >> 2);
    const int colb = ((lane & 3) * 16) ^ (((lane >> 3) & 3) << 4);  // pre-swz
    async_load16(base + (size_t)row * 1024 + koff + colb,
                 slot + c * 1024 + lane * 16);
  }
}

__device__ __forceinline__ void cvt_write8(void* dst, const float4& f0,
                                           const float4& f1) {
  union { s16x8 v; __hip_bfloat16 b[8]; } u;
  u.b[0] = __float2bfloat16(f0.x); u.b[1] = __float2bfloat16(f0.y);
  u.b[2] = __float2bfloat16(f0.z); u.b[3] = __float2bfloat16(f0.w);
  u.b[4] = __float2bfloat16(f1.x); u.b[5] = __float2bfloat16(f1.y);
  u.b[6] = __float2bfloat16(f1.z); u.b[7] = __float2bfloat16(f1.w);
  *(s16x8*)dst = u.v;
}

__global__ __launch_bounds__(512, 2) void gemm_kernel(
    const float* __restrict__ xf,
    const float* __restrict__ hf,
    const __hip_bfloat16* __restrict__ Wb,
    __hip_bfloat16* __restrict__ G)
{
  const int bid   = blockIdx.x;     // 256
  const int type  = bid & 1;        // 0 = X, 1 = H
  const int mband = bid >> 1;       // 0..127
  const int m0    = mband * 128;
  const float* Af = (type ? hf : xf) + (size_t)m0 * 512;

  __shared__ __align__(16) char lds[163840];

  const int tid  = threadIdx.x;
  const int lane = tid & 63;
  const int wave = tid >> 6;
  const int wm = wave >> 2, wn = wave & 3;   // 2 x 4 wave grid, 64x64 each

  const int lk  = (lane >> 4) * 16;
  const int lr  = lane & 15;
  const int rdk = lk ^ (((lr >> 1) & 3) << 4);     // read swizzle (A and B)

  auto rdA = [&](int kt, int fm) {
    return *(const s16x8*)(lds + kt * 8192 +
                           (wm * 64 + fm * 16 + lr) * 64 + rdk);
  };
  auto rdB = [&](int slot, int fn) {
    return *(const s16x8*)(lds + B_BASE + slot * 16384 +
                           (wn * 64 + fn * 16 + lr) * 64 + rdk);
  };

  // first B panel (n-tile list element 0)
  const int ntl0 = type ? 4 : 0;
  const char* Bb0 = (const char*)Wb + (size_t)ntl0 * 256 * 1024;

  // issue B(ktile 0) first so it's oldest in the vmem queue
  stage_B(Bb0, lds + B_BASE, 0, wave, lane);

  // ---- A streaming setup: LINEAR source, SWIZZLED LDS dest (rule 21) ----
  const int arow = tid >> 2;                         // 0..127
  const int alin = (tid & 3) * 16;                   // linear byte pos
  const int acb  = alin ^ (((arow >> 1) & 3) << 4);  // swizzled LDS pos
  const float* abase = Af + (size_t)arow * 512 + (alin >> 1);
  char* const awr = lds + arow * 64 + acb;           // + kt*8192

  float4 hA, hB;
  {
    const float4 a0 = *(const float4*)(abase);       // A(0)
    const float4 a1 = *(const float4*)(abase + 4);
    hA = *(const float4*)(abase + 32);               // A(1)
    hB = *(const float4*)(abase + 36);
    cvt_write8(awr, a0, a1);                         // write A(0)
  }

  // ---- panel 0: compute ntl0 while streaming A into residence ----
  {
    const int ntl1 = type ? 5 : 1;
    const char* BbN = (const char*)Wb + (size_t)ntl1 * 256 * 1024;

    f32x4 acc[4][4];
#pragma unroll
    for (int a = 0; a < 4; ++a)
#pragma unroll
      for (int b = 0; b < 4; ++b) acc[a][b] = (f32x4){0.f, 0.f, 0.f, 0.f};

#pragma unroll
    for (int kt = 0; kt < 16; ++kt) {
      asm volatile("s_waitcnt vmcnt(0) lgkmcnt(0)" ::: "memory");
      __builtin_amdgcn_s_barrier();   // B(kt) + A(kt+1) loads retired;
                                      // A(kt) writes visible

      if (kt <= 14) cvt_write8(awr + (kt + 1) * 8192, hA, hB);  // A(kt+1)

      const int slot = kt & 1;
      s16x8 b[4], a[4];
#pragma unroll
      for (int fn = 0; fn < 4; ++fn) b[fn] = rdB(slot, fn);
#pragma unroll
      for (int fm = 0; fm < 4; ++fm) a[fm] = rdA(kt, fm);

      if (kt < 15)
        stage_B(Bb0, lds + B_BASE + ((kt + 1) & 1) * 16384, (kt + 1) * 64,
                wave, lane);
      else
        stage_B(BbN, lds + B_BASE, 0, wave, lane);   // panel 1, slot 0

      if (kt <= 13) {                                 // load A(kt+2)
        hA = *(const float4*)(abase + (kt + 2) * 32);
        hB = *(const float4*)(abase + (kt + 2) * 32 + 4);
      }

      __builtin_amdgcn_s_setprio(1);
#pragma unroll
      for (int fm = 0; fm < 4; ++fm)
#pragma unroll
        for (int fn = 0; fn < 4; ++fn)
          acc[fm][fn] = __builtin_amdgcn_mfma_f32_16x16x32_bf16(
              a[fm], b[fn], acc[fm][fn], 0, 0, 0);
      __builtin_amdgcn_s_setprio(0);
    }

    // panel-0 epilogue
    const int n0 = ntl0 * 256;
    const int mbase = m0 + wm * 64 + ((lane >> 4) << 2);
    const int nbase = n0 + wn * 64 + lr;
#pragma unroll
    for (int fm = 0; fm < 4; ++fm)
#pragma unroll
      for (int fn = 0; fn < 4; ++fn)
#pragma unroll
        for (int r = 0; r < 4; ++r)
          G[(size_t)(mbase + fm * 16 + r) * 3072 + nbase + fn * 16] =
              __float2bfloat16(acc[fm][fn][r]);
  }

  // ---- panels 1..5 (A resident, immutable): A-frag prefetch + early B ----
  for (int i = 1; i < 6; ++i) {
    const int ntl = (i < 4) ? (type ? i + 4 : i) : (type ? i + 6 : i + 4);
    const int ntlN = (i + 1 < 4) ? (type ? i + 5 : i + 1)
                                 : (type ? i + 7 : i + 5);   // valid for i<5
    const char* Bb  = (const char*)Wb + (size_t)ntl * 256 * 1024;
    const char* BbN = (const char*)Wb + (size_t)(i < 5 ? ntlN : ntl) * 256 * 1024;

    f32x4 acc[4][4];
#pragma unroll
    for (int a = 0; a < 4; ++a)
#pragma unroll
      for (int b = 0; b < 4; ++b) acc[a][b] = (f32x4){0.f, 0.f, 0.f, 0.f};

    s16x8 aC[4];
#pragma unroll
    for (int kt = 0; kt < 16; ++kt) {
      asm volatile("s_waitcnt vmcnt(0)" ::: "memory");  // B(this kt) resident
      __builtin_amdgcn_s_barrier();                     // + prev reads done

      // early stage (WAR-safe: slot (kt+1)&1's readers finished at kt-1)
      if (kt < 15)
        stage_B(Bb, lds + B_BASE + ((kt + 1) & 1) * 16384, (kt + 1) * 64,
                wave, lane);
      else if (i < 5)
        stage_B(BbN, lds + B_BASE, 0, wave, lane);   // slot (16(i+1))&1 == 0

      const int slot = kt & 1;
      s16x8 b[4];
#pragma unroll
      for (int fn = 0; fn < 4; ++fn) b[fn] = rdB(slot, fn);
      if (kt == 0) {
#pragma unroll
        for (int fm = 0; fm < 4; ++fm) aC[fm] = rdA(0, fm);
      }

      __builtin_amdgcn_s_setprio(1);
#pragma unroll
      for (int fm = 0; fm < 2; ++fm)
#pragma unroll
        for (int fn = 0; fn < 4; ++fn)
          acc[fm][fn] = __builtin_amdgcn_mfma_f32_16x16x32_bf16(
              aC[fm], b[fn], acc[fm][fn], 0, 0, 0);

      s16x8 aN[4];
      if (kt < 15) {  // prefetch next ktile's A frags under the MFMA shadow
#pragma unroll
        for (int fm = 0; fm < 4; ++fm) aN[fm] = rdA(kt + 1, fm);
      }

#pragma unroll
      for (int fm = 2; fm < 4; ++fm)
#pragma unroll
        for (int fn = 0; fn < 4; ++fn)
          acc[fm][fn] = __builtin_amdgcn_mfma_f32_16x16x32_bf16(
              aC[fm], b[fn], acc[fm][fn], 0, 0, 0);
      __builtin_amdgcn_s_setprio(0);

      if (kt < 15) {
#pragma unroll
        for (int fm = 0; fm < 4; ++fm) aC[fm] = aN[fm];
      }
    }

    // n-tile epilogue: D lane map (verified): col=lane&15, row=(lane>>4)*4+r
    const int n0 = ntl * 256;
    const int mbase = m0 + wm * 64 + ((lane >> 4) << 2);
    const int nbase = n0 + wn * 64 + lr;
#pragma unroll
    for (int fm = 0; fm < 4; ++fm)
#pragma unroll
      for (int fn = 0; fn < 4; ++fn)
#pragma unroll
        for (int r = 0; r < 4; ++r)
          G[(size_t)(mbase + fm * 16 + r) * 3072 + nbase + fn * 16] =
              __float2bfloat16(acc[fm][fn][r]);
  }
}

// ------------------------------ LN + gates ---------------------------------
__device__ __forceinline__ float4 block_red4(float4 v, float* red, int tid) {
#pragma unroll
  for (int off = 32; off; off >>= 1) {
    v.x += __shfl_down(v.x, off);
    v.y += __shfl_down(v.y, off);
    v.z += __shfl_down(v.z, off);
    v.w += __shfl_down(v.w, off);
  }
  __syncthreads();  // protect `red` against previous use
  if ((tid & 63) == 0) {
    const int w = tid >> 6;
    red[w * 4 + 0] = v.x; red[w * 4 + 1] = v.y;
    red[w * 4 + 2] = v.z; red[w * 4 + 3] = v.w;
  }
  __syncthreads();
  return make_float4(red[0] + red[4] + red[8]  + red[12],
                     red[1] + red[5] + red[9]  + red[13],
                     red[2] + red[6] + red[10] + red[14],
                     red[3] + red[7] + red[11] + red[15]);
}

__global__ __launch_bounds__(256) void ln_gate_kernel(
    const __hip_bfloat16* __restrict__ G, const float* __restrict__ h,
    const float* __restrict__ b0, const float* __restrict__ b1,
    const float* __restrict__ b2, const float* __restrict__ b3,
    float* __restrict__ out)
{
  const int row = blockIdx.x;
  const int t   = threadIdx.x;
  const unsigned short* g = (const unsigned short*)(G + (size_t)row * 3072);

  __shared__ float zr[1024];
  __shared__ float red[16];

  float v0[4], v1[4];
  {
    const ushort4 u = *(const ushort4*)(g + 4 * t);
    const float4 b = *(const float4*)(b0 + 4 * t);
    v0[0] = bfraw2f(u.x) + b.x; v0[1] = bfraw2f(u.y) + b.y;
    v0[2] = bfraw2f(u.z) + b.z; v0[3] = bfraw2f(u.w) + b.w;
  }
  {
    const ushort4 u = *(const ushort4*)(g + 1024 + 4 * t);
    const float4 b = *(const float4*)(b1 + 4 * t);
    v1[0] = bfraw2f(u.x) + b.x; v1[1] = bfraw2f(u.y) + b.y;
    v1[2] = bfraw2f(u.z) + b.z; v1[3] = bfraw2f(u.w) + b.w;
  }
  float4 a;
  a.x = v0[0] + v0[1] + v0[2] + v0[3];
  a.y = v0[0]*v0[0] + v0[1]*v0[1] + v0[2]*v0[2] + v0[3]*v0[3];
  a.z = v1[0] + v1[1] + v1[2] + v1[3];
  a.w = v1[0]*v1[0] + v1[1]*v1[1] + v1[2]*v1[2] + v1[3]*v1[3];
  const float4 r01 = block_red4(a, red, t);
  const float mu0 = r01.x * (1.f / 1024.f);
  const float mu1 = r01.z * (1.f / 1024.f);
  const float rs0 = rsqrtf(r01.y * (1.f / 1024.f) - mu0 * mu0 + 1e-5f);
  const float rs1 = rsqrtf(r01.w * (1.f / 1024.f) - mu1 * mu1 + 1e-5f);

#pragma unroll
  for (int k = 0; k < 4; ++k) {
    const float pre = (v0[k] - mu0) * rs0 + (v1[k] - mu1) * rs1;
    zr[4 * t + k] = 1.f / (1.f + __expf(-pre));
  }

  float v2[2], v3[2];
  {
    const ushort2 u = *(const ushort2*)(g + 2048 + 2 * t);
    const float2 b = *(const float2*)(b2 + 2 * t);
    v2[0] = bfraw2f(u.x) + b.x; v2[1] = bfraw2f(u.y) + b.y;
  }
  {
    const ushort2 u = *(const ushort2*)(g + 2560 + 2 * t);
    const float2 b = *(const float2*)(b3 + 2 * t);
    v3[0] = bfraw2f(u.x) + b.x; v3[1] = bfraw2f(u.y) + b.y;
  }
  a.x = v2[0] + v2[1];
  a.y = v2[0]*v2[0] + v2[1]*v2[1];
  a.z = v3[0] + v3[1];
  a.w = v3[0]*v3[0] + v3[1]*v3[1];
  const float4 r23 = block_red4(a, red, t);  // syncs also publish zr[]
  const float mu2 = r23.x * (1.f / 512.f);
  const float mu3 = r23.z * (1.f / 512.f);
  const float rs2 = rsqrtf(r23.y * (1.f / 512.f) - mu2 * mu2 + 1e-5f);
  const float rs3 = rsqrtf(r23.w * (1.f / 512.f) - mu3 * mu3 + 1e-5f);

  const float2 hv = *(const float2*)(h + (size_t)row * 512 + 2 * t);
  float o[2];
#pragma unroll
  for (int k = 0; k < 2; ++k) {
    const int j = 2 * t + k;
    const float ha = (v2[k] - mu2) * rs2;
    const float hbv = (v3[k] - mu3) * rs3;
    const float hhat = tanhf(ha + zr[512 + j] * hbv);
    const float z = zr[j];
    const float hvk = (k == 0) ? hv.x : hv.y;
    o[k] = (1.f - z) * hvk + z * hhat;
  }
  *(float2*)(out + (size_t)row * 512 + 2 * t) = make_float2(o[0], o[1]);
}

// ------------------------------- launcher ----------------------------------
extern "C" void kernel_launch(void* const* d_in, const int* in_sizes, int n_in,
                              void* d_out, int out_size, void* d_ws, size_t ws_size,
                              hipStream_t stream) {
  (void)in_sizes; (void)n_in; (void)out_size; (void)ws_size;
  const float* x      = (const float*)d_in[0];
  const float* h      = (const float*)d_in[1];
  const float* W_i2h  = (const float*)d_in[2];
  const float* b_i2h  = (const float*)d_in[3];
  const float* W_h2h  = (const float*)d_in[4];
  const float* b_h2h  = (const float*)d_in[5];
  const float* W_hatW = (const float*)d_in[6];
  const float* b_hatW = (const float*)d_in[7];
  const float* W_hatU = (const float*)d_in[8];
  const float* b_hatU = (const float*)d_in[9];
  float* out = (float*)d_out;
  __hip_bfloat16* ws = (__hip_bfloat16*)d_ws;

  convert_w_kernel<<<1536, 256, 0, stream>>>(W_i2h, W_h2h, W_hatW, W_hatU,
                                             ws + WB_OFF);
  gemm_kernel<<<256, 512, 0, stream>>>(x, h, ws + WB_OFF, ws + GB_OFF);
  ln_gate_kernel<<<16384, 256, 0, stream>>>(ws + GB_OFF, h, b_i2h, b_h2h,
                                            b_hatW, b_hatU, out);
}

// Round 19
// 105.674 us; speedup vs baseline: 1.2430x; 1.1417x over previous
//
#include <hip/hip_runtime.h>
#include <hip/hip_bf16.h>

// ---------------------------------------------------------------------------
// LayerNormGRUCell: B=16384, I=H=512
//   G = [x@W_i2h.T | h@W_h2h.T | x@W_hatW.T | h@W_hatU.T]  (16384 x 3072)
//   then per-row: LN segments + gates + tanh + lerp -> h_t (16384 x 512 fp32)
// ws layout (bf16 elements):
//   Wcat @ 0        (3072*512)    rows: [W_i2h;W_h2h;W_hatW;W_hatU]
//   Gb   @ 1572864  (16384*3072)
// Round-19: WAVE-PER-ROW ln_gate (zero __syncthreads, 16B loads, butterfly
// shfl reductions, transposed conflict-free zr LDS). gemm/convert_w = r18.
// ---------------------------------------------------------------------------

using f32x4 = __attribute__((ext_vector_type(4))) float;
using s16x8 = __attribute__((ext_vector_type(8))) short;
typedef __attribute__((ext_vector_type(8))) unsigned short u16x8;

#define WB_OFF   0ull
#define GB_OFF   1572864ull

__device__ __forceinline__ void async_load16(const void* g, void* l) {
  __builtin_amdgcn_global_load_lds(
      (const __attribute__((address_space(1))) unsigned int*)g,
      (__attribute__((address_space(3))) unsigned int*)l, 16, 0, 0);
}

__device__ __forceinline__ float bfraw2f(unsigned short u) {
  union { unsigned int i; float f; } c;
  c.i = ((unsigned int)u) << 16;
  return c.f;
}

// -------------------------- fp32 -> bf16 weights only ----------------------
__global__ __launch_bounds__(256) void convert_w_kernel(
    const float* __restrict__ w0, const float* __restrict__ w1,
    const float* __restrict__ w2, const float* __restrict__ w3,
    __hip_bfloat16* __restrict__ dst)
{
  const size_t i = (size_t)blockIdx.x * 256 + threadIdx.x;  // vec4 index
  const float* src;
  __hip_bfloat16* d;
  size_t o;
  if (i < 131072ull)      { src = w0; d = dst;            o = i; }
  else if (i < 262144ull) { src = w1; d = dst + 524288;   o = i - 131072ull; }
  else if (i < 327680ull) { src = w2; d = dst + 1048576;  o = i - 262144ull; }
  else                    { src = w3; d = dst + 1310720;  o = i - 327680ull; }
  const float4 v = *(const float4*)(src + 4 * o);
  __hip_bfloat16 t4[4] = {__float2bfloat16(v.x), __float2bfloat16(v.y),
                          __float2bfloat16(v.z), __float2bfloat16(v.w)};
  *(uint2*)(d + 4 * o) = *(const uint2*)t4;
}

// -------------------------------- GEMM (r18 verbatim) ----------------------
#define B_BASE 131072

__device__ __forceinline__ void stage_B(const char* base, char* slot,
                                        int koff, int wave, int lane) {
#pragma unroll
  for (int i = 0; i < 2; ++i) {
    const int c = wave * 2 + i;
    const int row  = c * 16 + (lane >> 2);
    const int colb = ((lane & 3) * 16) ^ (((lane >> 3) & 3) << 4);  // pre-swz
    async_load16(base + (size_t)row * 1024 + koff + colb,
                 slot + c * 1024 + lane * 16);
  }
}

__device__ __forceinline__ void cvt_write8(void* dst, const float4& f0,
                                           const float4& f1) {
  union { s16x8 v; __hip_bfloat16 b[8]; } u;
  u.b[0] = __float2bfloat16(f0.x); u.b[1] = __float2bfloat16(f0.y);
  u.b[2] = __float2bfloat16(f0.z); u.b[3] = __float2bfloat16(f0.w);
  u.b[4] = __float2bfloat16(f1.x); u.b[5] = __float2bfloat16(f1.y);
  u.b[6] = __float2bfloat16(f1.z); u.b[7] = __float2bfloat16(f1.w);
  *(s16x8*)dst = u.v;
}

__global__ __launch_bounds__(512, 2) void gemm_kernel(
    const float* __restrict__ xf,
    const float* __restrict__ hf,
    const __hip_bfloat16* __restrict__ Wb,
    __hip_bfloat16* __restrict__ G)
{
  const int bid   = blockIdx.x;     // 256
  const int type  = bid & 1;        // 0 = X, 1 = H
  const int mband = bid >> 1;       // 0..127
  const int m0    = mband * 128;
  const float* Af = (type ? hf : xf) + (size_t)m0 * 512;

  __shared__ __align__(16) char lds[163840];

  const int tid  = threadIdx.x;
  const int lane = tid & 63;
  const int wave = tid >> 6;
  const int wm = wave >> 2, wn = wave & 3;   // 2 x 4 wave grid, 64x64 each

  const int lk  = (lane >> 4) * 16;
  const int lr  = lane & 15;
  const int rdk = lk ^ (((lr >> 1) & 3) << 4);     // read swizzle (A and B)

  auto rdA = [&](int kt, int fm) {
    return *(const s16x8*)(lds + kt * 8192 +
                           (wm * 64 + fm * 16 + lr) * 64 + rdk);
  };
  auto rdB = [&](int slot, int fn) {
    return *(const s16x8*)(lds + B_BASE + slot * 16384 +
                           (wn * 64 + fn * 16 + lr) * 64 + rdk);
  };

  const int ntl0 = type ? 4 : 0;
  const char* Bb0 = (const char*)Wb + (size_t)ntl0 * 256 * 1024;

  stage_B(Bb0, lds + B_BASE, 0, wave, lane);

  const int arow = tid >> 2;                         // 0..127
  const int alin = (tid & 3) * 16;                   // linear byte pos
  const int acb  = alin ^ (((arow >> 1) & 3) << 4);  // swizzled LDS pos
  const float* abase = Af + (size_t)arow * 512 + (alin >> 1);
  char* const awr = lds + arow * 64 + acb;           // + kt*8192

  float4 hA, hB;
  {
    const float4 a0 = *(const float4*)(abase);       // A(0)
    const float4 a1 = *(const float4*)(abase + 4);
    hA = *(const float4*)(abase + 32);               // A(1)
    hB = *(const float4*)(abase + 36);
    cvt_write8(awr, a0, a1);                         // write A(0)
  }

  // ---- panel 0: compute ntl0 while streaming A into residence ----
  {
    const int ntl1 = type ? 5 : 1;
    const char* BbN = (const char*)Wb + (size_t)ntl1 * 256 * 1024;

    f32x4 acc[4][4];
#pragma unroll
    for (int a = 0; a < 4; ++a)
#pragma unroll
      for (int b = 0; b < 4; ++b) acc[a][b] = (f32x4){0.f, 0.f, 0.f, 0.f};

#pragma unroll
    for (int kt = 0; kt < 16; ++kt) {
      asm volatile("s_waitcnt vmcnt(0) lgkmcnt(0)" ::: "memory");
      __builtin_amdgcn_s_barrier();

      if (kt <= 14) cvt_write8(awr + (kt + 1) * 8192, hA, hB);  // A(kt+1)

      const int slot = kt & 1;
      s16x8 b[4], a[4];
#pragma unroll
      for (int fn = 0; fn < 4; ++fn) b[fn] = rdB(slot, fn);
#pragma unroll
      for (int fm = 0; fm < 4; ++fm) a[fm] = rdA(kt, fm);

      if (kt < 15)
        stage_B(Bb0, lds + B_BASE + ((kt + 1) & 1) * 16384, (kt + 1) * 64,
                wave, lane);
      else
        stage_B(BbN, lds + B_BASE, 0, wave, lane);   // panel 1, slot 0

      if (kt <= 13) {                                 // load A(kt+2)
        hA = *(const float4*)(abase + (kt + 2) * 32);
        hB = *(const float4*)(abase + (kt + 2) * 32 + 4);
      }

      __builtin_amdgcn_s_setprio(1);
#pragma unroll
      for (int fm = 0; fm < 4; ++fm)
#pragma unroll
        for (int fn = 0; fn < 4; ++fn)
          acc[fm][fn] = __builtin_amdgcn_mfma_f32_16x16x32_bf16(
              a[fm], b[fn], acc[fm][fn], 0, 0, 0);
      __builtin_amdgcn_s_setprio(0);
    }

    const int n0 = ntl0 * 256;
    const int mbase = m0 + wm * 64 + ((lane >> 4) << 2);
    const int nbase = n0 + wn * 64 + lr;
#pragma unroll
    for (int fm = 0; fm < 4; ++fm)
#pragma unroll
      for (int fn = 0; fn < 4; ++fn)
#pragma unroll
        for (int r = 0; r < 4; ++r)
          G[(size_t)(mbase + fm * 16 + r) * 3072 + nbase + fn * 16] =
              __float2bfloat16(acc[fm][fn][r]);
  }

  // ---- panels 1..5 (A resident, immutable): A-frag prefetch + early B ----
  for (int i = 1; i < 6; ++i) {
    const int ntl = (i < 4) ? (type ? i + 4 : i) : (type ? i + 6 : i + 4);
    const int ntlN = (i + 1 < 4) ? (type ? i + 5 : i + 1)
                                 : (type ? i + 7 : i + 5);   // valid for i<5
    const char* Bb  = (const char*)Wb + (size_t)ntl * 256 * 1024;
    const char* BbN = (const char*)Wb + (size_t)(i < 5 ? ntlN : ntl) * 256 * 1024;

    f32x4 acc[4][4];
#pragma unroll
    for (int a = 0; a < 4; ++a)
#pragma unroll
      for (int b = 0; b < 4; ++b) acc[a][b] = (f32x4){0.f, 0.f, 0.f, 0.f};

    s16x8 aC[4];
#pragma unroll
    for (int kt = 0; kt < 16; ++kt) {
      asm volatile("s_waitcnt vmcnt(0)" ::: "memory");
      __builtin_amdgcn_s_barrier();

      if (kt < 15)
        stage_B(Bb, lds + B_BASE + ((kt + 1) & 1) * 16384, (kt + 1) * 64,
                wave, lane);
      else if (i < 5)
        stage_B(BbN, lds + B_BASE, 0, wave, lane);

      const int slot = kt & 1;
      s16x8 b[4];
#pragma unroll
      for (int fn = 0; fn < 4; ++fn) b[fn] = rdB(slot, fn);
      if (kt == 0) {
#pragma unroll
        for (int fm = 0; fm < 4; ++fm) aC[fm] = rdA(0, fm);
      }

      __builtin_amdgcn_s_setprio(1);
#pragma unroll
      for (int fm = 0; fm < 2; ++fm)
#pragma unroll
        for (int fn = 0; fn < 4; ++fn)
          acc[fm][fn] = __builtin_amdgcn_mfma_f32_16x16x32_bf16(
              aC[fm], b[fn], acc[fm][fn], 0, 0, 0);

      s16x8 aN[4];
      if (kt < 15) {
#pragma unroll
        for (int fm = 0; fm < 4; ++fm) aN[fm] = rdA(kt + 1, fm);
      }

#pragma unroll
      for (int fm = 2; fm < 4; ++fm)
#pragma unroll
        for (int fn = 0; fn < 4; ++fn)
          acc[fm][fn] = __builtin_amdgcn_mfma_f32_16x16x32_bf16(
              aC[fm], b[fn], acc[fm][fn], 0, 0, 0);
      __builtin_amdgcn_s_setprio(0);

      if (kt < 15) {
#pragma unroll
        for (int fm = 0; fm < 4; ++fm) aC[fm] = aN[fm];
      }
    }

    const int n0 = ntl * 256;
    const int mbase = m0 + wm * 64 + ((lane >> 4) << 2);
    const int nbase = n0 + wn * 64 + lr;
#pragma unroll
    for (int fm = 0; fm < 4; ++fm)
#pragma unroll
      for (int fn = 0; fn < 4; ++fn)
#pragma unroll
        for (int r = 0; r < 4; ++r)
          G[(size_t)(mbase + fm * 16 + r) * 3072 + nbase + fn * 16] =
              __float2bfloat16(acc[fm][fn][r]);
  }
}

// ------------------------------ LN + gates (wave-per-row) ------------------
// One wave per row: no __syncthreads. Lane L owns gate cols 16L..16L+15 and
// hat cols 8L..8L+7. Reductions = 6-step __shfl_xor butterflies. z/r handoff
// via per-wave LDS in TRANSPOSED layout zr[c] -> [(c&15)*64 + (c>>4)]:
// writes lane-stride 4B (conflict-free); reads 2 lanes/bank (free, m136).
// Same-wave DS ops are in-order; lgkmcnt(0) before the reads for safety.
__global__ __launch_bounds__(256) void ln_gate_kernel(
    const __hip_bfloat16* __restrict__ G, const float* __restrict__ h,
    const float* __restrict__ b0, const float* __restrict__ b1,
    const float* __restrict__ b2, const float* __restrict__ b3,
    float* __restrict__ out)
{
  const int w = threadIdx.x >> 6;
  const int L = threadIdx.x & 63;
  const int row = blockIdx.x * 4 + w;
  const unsigned short* g = (const unsigned short*)(G + (size_t)row * 3072);

  __shared__ float zr[4][1024];   // transposed: col c at (c&15)*64 + (c>>4)
  float* const zw = zr[w];

  // gates: v0 = i2h cols 16L..16L+15, v1 = h2h same cols
  float v0[16], v1[16];
  {
    const u16x8 a0 = *(const u16x8*)(g + 16 * L);
    const u16x8 a1 = *(const u16x8*)(g + 16 * L + 8);
    const u16x8 c0 = *(const u16x8*)(g + 1024 + 16 * L);
    const u16x8 c1 = *(const u16x8*)(g + 1024 + 16 * L + 8);
#pragma unroll
    for (int q = 0; q < 4; ++q) {
      const float4 f0 = *(const float4*)(b0 + 16 * L + 4 * q);
      const float4 f1 = *(const float4*)(b1 + 16 * L + 4 * q);
      const float bb0[4] = {f0.x, f0.y, f0.z, f0.w};
      const float bb1[4] = {f1.x, f1.y, f1.z, f1.w};
#pragma unroll
      for (int j = 0; j < 4; ++j) {
        const int k = 4 * q + j;
        const unsigned short ua = (k < 8) ? a0[k] : a1[k - 8];
        const unsigned short uc = (k < 8) ? c0[k] : c1[k - 8];
        v0[k] = bfraw2f(ua) + bb0[j];
        v1[k] = bfraw2f(uc) + bb1[j];
      }
    }
  }
  float4 s = make_float4(0.f, 0.f, 0.f, 0.f);
#pragma unroll
  for (int k = 0; k < 16; ++k) {
    s.x += v0[k]; s.y += v0[k] * v0[k];
    s.z += v1[k]; s.w += v1[k] * v1[k];
  }
#pragma unroll
  for (int off = 1; off < 64; off <<= 1) {
    s.x += __shfl_xor(s.x, off);
    s.y += __shfl_xor(s.y, off);
    s.z += __shfl_xor(s.z, off);
    s.w += __shfl_xor(s.w, off);
  }
  const float mu0 = s.x * (1.f / 1024.f);
  const float mu1 = s.z * (1.f / 1024.f);
  const float rs0 = rsqrtf(s.y * (1.f / 1024.f) - mu0 * mu0 + 1e-5f);
  const float rs1 = rsqrtf(s.w * (1.f / 1024.f) - mu1 * mu1 + 1e-5f);

#pragma unroll
  for (int k = 0; k < 16; ++k) {
    const float pre = (v0[k] - mu0) * rs0 + (v1[k] - mu1) * rs1;
    zw[k * 64 + L] = 1.f / (1.f + __expf(-pre));   // c = 16L+k transposed
  }

  // hats: v2 = hatW cols 8L..8L+7, v3 = hatU same cols
  float v2[8], v3[8];
  {
    const u16x8 a = *(const u16x8*)(g + 2048 + 8 * L);
    const u16x8 c = *(const u16x8*)(g + 2560 + 8 * L);
#pragma unroll
    for (int q = 0; q < 2; ++q) {
      const float4 f2 = *(const float4*)(b2 + 8 * L + 4 * q);
      const float4 f3 = *(const float4*)(b3 + 8 * L + 4 * q);
      const float bb2[4] = {f2.x, f2.y, f2.z, f2.w};
      const float bb3[4] = {f3.x, f3.y, f3.z, f3.w};
#pragma unroll
      for (int j = 0; j < 4; ++j) {
        const int k = 4 * q + j;
        v2[k] = bfraw2f(a[k]) + bb2[j];
        v3[k] = bfraw2f(c[k]) + bb3[j];
      }
    }
  }
  float4 t = make_float4(0.f, 0.f, 0.f, 0.f);
#pragma unroll
  for (int k = 0; k < 8; ++k) {
    t.x += v2[k]; t.y += v2[k] * v2[k];
    t.z += v3[k]; t.w += v3[k] * v3[k];
  }
#pragma unroll
  for (int off = 1; off < 64; off <<= 1) {
    t.x += __shfl_xor(t.x, off);
    t.y += __shfl_xor(t.y, off);
    t.z += __shfl_xor(t.z, off);
    t.w += __shfl_xor(t.w, off);
  }
  const float mu2 = t.x * (1.f / 512.f);
  const float mu3 = t.z * (1.f / 512.f);
  const float rs2 = rsqrtf(t.y * (1.f / 512.f) - mu2 * mu2 + 1e-5f);
  const float rs3 = rsqrtf(t.w * (1.f / 512.f) - mu3 * mu3 + 1e-5f);

  asm volatile("s_waitcnt lgkmcnt(0)" ::: "memory");  // zw writes done (same wave)

  const float4 h0 = *(const float4*)(h + (size_t)row * 512 + 8 * L);
  const float4 h1 = *(const float4*)(h + (size_t)row * 512 + 8 * L + 4);
  const float hv[8] = {h0.x, h0.y, h0.z, h0.w, h1.x, h1.y, h1.z, h1.w};

  float o[8];
#pragma unroll
  for (int k = 0; k < 8; ++k) {
    const int c  = 8 * L + k;                         // hat col
    // transposed fetch: col c -> (c&15)*64 + (c>>4); r at col 512+c
    const float z  = zw[(c & 15) * 64 + (c >> 4)];
    const float rr = zw[((512 + c) & 15) * 64 + ((512 + c) >> 4)];
    const float ha  = (v2[k] - mu2) * rs2;
    const float hbv = (v3[k] - mu3) * rs3;
    const float hhat = tanhf(ha + rr * hbv);
    o[k] = (1.f - z) * hv[k] + z * hhat;
  }
  *(float4*)(out + (size_t)row * 512 + 8 * L)     = make_float4(o[0], o[1], o[2], o[3]);
  *(float4*)(out + (size_t)row * 512 + 8 * L + 4) = make_float4(o[4], o[5], o[6], o[7]);
}

// ------------------------------- launcher ----------------------------------
extern "C" void kernel_launch(void* const* d_in, const int* in_sizes, int n_in,
                              void* d_out, int out_size, void* d_ws, size_t ws_size,
                              hipStream_t stream) {
  (void)in_sizes; (void)n_in; (void)out_size; (void)ws_size;
  const float* x      = (const float*)d_in[0];
  const float* h      = (const float*)d_in[1];
  const float* W_i2h  = (const float*)d_in[2];
  const float* b_i2h  = (const float*)d_in[3];
  const float* W_h2h  = (const float*)d_in[4];
  const float* b_h2h  = (const float*)d_in[5];
  const float* W_hatW = (const float*)d_in[6];
  const float* b_hatW = (const float*)d_in[7];
  const float* W_hatU = (const float*)d_in[8];
  const float* b_hatU = (const float*)d_in[9];
  float* out = (float*)d_out;
  __hip_bfloat16* ws = (__hip_bfloat16*)d_ws;

  convert_w_kernel<<<1536, 256, 0, stream>>>(W_i2h, W_h2h, W_hatW, W_hatU,
                                             ws + WB_OFF);
  gemm_kernel<<<256, 512, 0, stream>>>(x, h, ws + WB_OFF, ws + GB_OFF);
  ln_gate_kernel<<<4096, 256, 0, stream>>>(ws + GB_OFF, h, b_i2h, b_h2h,
                                           b_hatW, b_hatU, out);
}